// Round 5
// baseline (517.660 us; speedup 1.0000x reference)
//
#include <hip/hip_runtime.h>
#include <stdint.h>

#define T_TOK 16384
#define D_DIM 4096
#define E_EXP 128
#define TE ((size_t)T_TOK * E_EXP)

#define TAU 2.5e-3f
#define FLAG_CAP 8192
#define WT_OFF 65536
#define WT_ELEMS ((size_t)E_EXP * D_DIM)   // 524288

#define NSPLIT 2
#define KLEN (D_DIM / NSPLIT)              // 2048
#define BMg 128
#define BKg 64

typedef __attribute__((ext_vector_type(8))) _Float16 half8;
typedef __attribute__((ext_vector_type(4))) float f32x4;

// ---------------- Threefry-2x32 (JAX-compatible) ----------------
#define TF_ROUND(x0, x1, r) { x0 += x1; x1 = (x1 << r) | (x1 >> (32 - r)); x1 ^= x0; }

__host__ __device__ inline void tf2x32(uint32_t k0, uint32_t k1, uint32_t x0, uint32_t x1,
                                       uint32_t* o0, uint32_t* o1) {
  uint32_t ks2 = k0 ^ k1 ^ 0x1BD11BDAu;
  x0 += k0; x1 += k1;
  TF_ROUND(x0, x1, 13) TF_ROUND(x0, x1, 15) TF_ROUND(x0, x1, 26) TF_ROUND(x0, x1, 6)
  x0 += k1; x1 += ks2 + 1u;
  TF_ROUND(x0, x1, 17) TF_ROUND(x0, x1, 29) TF_ROUND(x0, x1, 16) TF_ROUND(x0, x1, 24)
  x0 += ks2; x1 += k0 + 2u;
  TF_ROUND(x0, x1, 13) TF_ROUND(x0, x1, 15) TF_ROUND(x0, x1, 26) TF_ROUND(x0, x1, 6)
  x0 += k0; x1 += k1 + 3u;
  TF_ROUND(x0, x1, 17) TF_ROUND(x0, x1, 29) TF_ROUND(x0, x1, 16) TF_ROUND(x0, x1, 24)
  x0 += k1; x1 += ks2 + 4u;
  TF_ROUND(x0, x1, 13) TF_ROUND(x0, x1, 15) TF_ROUND(x0, x1, 26) TF_ROUND(x0, x1, 6)
  x0 += ks2; x1 += k0 + 5u;
  *o0 = x0; *o1 = x1;
}

__device__ inline uint32_t rng_bits(uint32_t j, uint32_t fk0, uint32_t fk1) {
  uint32_t o0, o1;
  tf2x32(fk0, fk1, 0u, j, &o0, &o1);
  return o0 ^ o1;
}

// gumbel = -log(-log(u)). Inner log kept precise (near u~1 its absolute error is
// amplified by the outer log); outer log's near-1 region maps to gumbel~0 where
// absolute error stays ~1e-7, so the fast hw log is safe there.
__device__ inline float gumbel_f32(uint32_t j, uint32_t fk0, uint32_t fk1) {
  uint32_t bits = rng_bits(j, fk0, fk1);
  float f = __uint_as_float((bits >> 9) | 0x3f800000u) - 1.0f;
  const float mn = 1e-6f;
  const float mx = (float)(1.0 - 1e-6);
  float u = fmaxf(mn, f * (mx - mn) + mn);
  float nl = -logf(u);
  return -__logf(nl);
}

__device__ inline double gumbel_f64(uint32_t j, uint32_t fk0, uint32_t fk1) {
  uint32_t bits = rng_bits(j, fk0, fk1);
  float f = __uint_as_float((bits >> 9) | 0x3f800000u) - 1.0f;
  const float mn = 1e-6f;
  const float mx = (float)(1.0 - 1e-6);
  float u = fmaxf(mn, f * (mx - mn) + mn);
  return -log(-log((double)u));
}

// async global->LDS, 16B per lane; LDS dest must be wave-uniform base (+lane*16 implicit)
__device__ __forceinline__ void gload_lds16(const void* g, void* l) {
  __builtin_amdgcn_global_load_lds(
      (const __attribute__((address_space(1))) unsigned int*)g,
      (__attribute__((address_space(3))) unsigned int*)l, 16, 0, 0);
}

// ---------------- prep: W[k][e] -> fragment-order fp16 ----------------
// Slot (kb 0..127, cg 0..7, ln 0..63) holds W[kb*32 + (ln>>4)*8 + j][cg*16 + (ln&15)],
// j=0..7, at linear offset slot*8 — exact MFMA B-fragment order, so GEMM staging is a
// pure linear 16B/lane copy. Single fp16 array (2-pass scheme drops the W residual:
// error ~2^-11 relative, guarded by TAU + f64 recompute).
__global__ __launch_bounds__(256) void prep_kernel(const float* __restrict__ W,
                                                   _Float16* __restrict__ WF16,
                                                   int* __restrict__ wsi) {
  if (blockIdx.x == 0 && threadIdx.x < 16) wsi[threadIdx.x] = 0;
  const int gslot = blockIdx.x * 256 + threadIdx.x;   // 0..65535
  const int kb  = gslot >> 9;
  const int rem = gslot & 511;
  const int cg  = rem >> 6;
  const int ln  = rem & 63;
  const int q = ln >> 4, m = ln & 15;
  const int e  = cg * 16 + m;
  const int k0 = kb * 32 + q * 8;

  __attribute__((aligned(16))) _Float16 hv[8];
  #pragma unroll
  for (int j = 0; j < 8; j++) {
    float w = W[(size_t)(k0 + j) * E_EXP + e];
    hv[j] = (_Float16)w;
  }
  *(uint4*)(WF16 + (size_t)gslot * 8) = *(const uint4*)hv;
}

// ---------------- MFMA GEMM: 128x128 tile, 8 waves (2x4), BK=64, split-K=2 ----------------
// fp16x2 scheme: A split into fp16 hi/lo in-kernel, B single fp16 (prep).
// Per (ks,r,c): 2 MFMA (Ahi*B + Alo*B). 32 K-steps, double-buffered, one barrier/step.
// LDS = 96 KB: sAhi/sAlo 2x16KB each, sB 2x16KB. 1 block/CU, 8 waves.
__global__ __launch_bounds__(512, 2) void gemm_mfma(const float* __restrict__ h,
                                                    const _Float16* __restrict__ WF16,
                                                    float* __restrict__ outbase) {
  __shared__ __align__(16) _Float16 sAhi[2][8192];   // 16 KB per buf, fragment order
  __shared__ __align__(16) _Float16 sAlo[2][8192];
  __shared__ __align__(16) _Float16 sB[2][8192];

  const int tid  = threadIdx.x;        // 0..511
  const int ln   = tid & 63;
  const int wv   = tid >> 6;           // 0..7
  const int m    = ln & 15;
  const int quad = ln >> 4;
  const int rh   = wv >> 2;            // token half (0/1)
  const int ch   = wv & 3;             // expert quarter (0..3)
  const int t0   = blockIdx.x * BMg;
  const int kbase = blockIdx.y * KLEN;

  // A staging: thread fills fragment slots tid (k-slice 0) and tid+512 (k-slice 1),
  // row wv*16+m, k columns quad*8+{0..7} and 32+quad*8+{0..7}.
  const float* asrc = h + (size_t)(t0 + wv * 16 + m) * D_DIM + kbase + quad * 8;

  // B staging: two 8KB gload passes per buffer cover 8192 halves (2 k-blocks contiguous
  // in fragment-order global layout).
  const size_t gslot8 = (size_t)tid * 8;             // halves
  _Float16* bdst[2][2] = {{ &sB[0][wv * 512], &sB[0][4096 + wv * 512] },
                          { &sB[1][wv * 512], &sB[1][4096 + wv * 512] }};

  f32x4 acc[4][2];
  #pragma unroll
  for (int r = 0; r < 4; r++)
    #pragma unroll
    for (int c = 0; c < 2; c++) acc[r][c] = (f32x4){0.f, 0.f, 0.f, 0.f};

  // ---- prologue: stage k0 = 0 into buffer 0 ----
  {
    const size_t boff = ((size_t)(kbase >> 5)) * 4096;
    gload_lds16(WF16 + boff + gslot8,        bdst[0][0]);
    gload_lds16(WF16 + boff + 4096 + gslot8, bdst[0][1]);

    float4 a0 = *(const float4*)(asrc);
    float4 a1 = *(const float4*)(asrc + 4);
    float4 a2 = *(const float4*)(asrc + 32);
    float4 a3 = *(const float4*)(asrc + 36);
    float v0[8] = {a0.x, a0.y, a0.z, a0.w, a1.x, a1.y, a1.z, a1.w};
    float v1[8] = {a2.x, a2.y, a2.z, a2.w, a3.x, a3.y, a3.z, a3.w};
    __attribute__((aligned(16))) _Float16 h0[8], l0[8], h1[8], l1[8];
    #pragma unroll
    for (int j = 0; j < 8; j++) {
      _Float16 t16 = (_Float16)v0[j]; h0[j] = t16; l0[j] = (_Float16)(v0[j] - (float)t16);
      t16 = (_Float16)v1[j];          h1[j] = t16; l1[j] = (_Float16)(v1[j] - (float)t16);
    }
    *(uint4*)&sAhi[0][(size_t)tid * 8]         = *(const uint4*)h0;
    *(uint4*)&sAlo[0][(size_t)tid * 8]         = *(const uint4*)l0;
    *(uint4*)&sAhi[0][(size_t)(tid + 512) * 8] = *(const uint4*)h1;
    *(uint4*)&sAlo[0][(size_t)(tid + 512) * 8] = *(const uint4*)l1;
    __syncthreads();   // drains vmcnt(0) (B DMA) + lgkm (A writes)
  }

  int cur = 0;
  for (int k0 = 0; k0 < KLEN; k0 += BKg) {
    const int kn  = k0 + BKg;
    const bool nxt = (kn < KLEN);
    float4 a0, a1, a2, a3;

    if (nxt) {
      // issue next-tile B straight to LDS (other buffer) + next A into regs
      const int nb = cur ^ 1;
      const size_t boff = ((size_t)((kbase + kn) >> 5)) * 4096;
      gload_lds16(WF16 + boff + gslot8,        bdst[nb][0]);
      gload_lds16(WF16 + boff + 4096 + gslot8, bdst[nb][1]);
      a0 = *(const float4*)(asrc + kn);
      a1 = *(const float4*)(asrc + kn + 4);
      a2 = *(const float4*)(asrc + kn + 32);
      a3 = *(const float4*)(asrc + kn + 36);
    }

    // ---- compute current buffer: 2 k-slices x (r4 x c2) x 2 MFMA ----
    half8 ahi[4][2], alo[4][2], bf[2][2];
    #pragma unroll
    for (int ks = 0; ks < 2; ks++) {
      #pragma unroll
      for (int r = 0; r < 4; r++) {
        const int slot = (ks * 512 + (rh * 4 + r) * 64 + ln) * 8;
        ahi[r][ks] = *(const half8*)&sAhi[cur][slot];
        alo[r][ks] = *(const half8*)&sAlo[cur][slot];
      }
      #pragma unroll
      for (int c = 0; c < 2; c++) {
        const int slot = (ks * 512 + (ch * 2 + c) * 64 + ln) * 8;
        bf[c][ks] = *(const half8*)&sB[cur][slot];
      }
    }
    #pragma unroll
    for (int ks = 0; ks < 2; ks++)
      #pragma unroll
      for (int r = 0; r < 4; r++)
        #pragma unroll
        for (int c = 0; c < 2; c++) {
          acc[r][c] = __builtin_amdgcn_mfma_f32_16x16x32_f16(ahi[r][ks], bf[c][ks], acc[r][c], 0, 0, 0);
          acc[r][c] = __builtin_amdgcn_mfma_f32_16x16x32_f16(alo[r][ks], bf[c][ks], acc[r][c], 0, 0, 0);
        }

    if (nxt) {
      // convert + write next A late (loads had the whole MFMA phase to land)
      const int nb = cur ^ 1;
      float v0[8] = {a0.x, a0.y, a0.z, a0.w, a1.x, a1.y, a1.z, a1.w};
      float v1[8] = {a2.x, a2.y, a2.z, a2.w, a3.x, a3.y, a3.z, a3.w};
      __attribute__((aligned(16))) _Float16 h0[8], l0[8], h1[8], l1[8];
      #pragma unroll
      for (int j = 0; j < 8; j++) {
        _Float16 t16 = (_Float16)v0[j]; h0[j] = t16; l0[j] = (_Float16)(v0[j] - (float)t16);
        t16 = (_Float16)v1[j];          h1[j] = t16; l1[j] = (_Float16)(v1[j] - (float)t16);
      }
      *(uint4*)&sAhi[nb][(size_t)tid * 8]         = *(const uint4*)h0;
      *(uint4*)&sAlo[nb][(size_t)tid * 8]         = *(const uint4*)l0;
      *(uint4*)&sAhi[nb][(size_t)(tid + 512) * 8] = *(const uint4*)h1;
      *(uint4*)&sAlo[nb][(size_t)(tid + 512) * 8] = *(const uint4*)l1;
    }
    __syncthreads();   // one barrier per K-step: drains B DMA + A writes
    cur ^= 1;
  }

  // partials for split s go straight into output region s (route re-reads + overwrites)
  float* ob = outbase + (size_t)blockIdx.y * TE;
  #pragma unroll
  for (int r = 0; r < 4; r++)
    #pragma unroll
    for (int c = 0; c < 2; c++) {
      const int e = ch * 32 + 16 * c + m;
      #pragma unroll
      for (int reg = 0; reg < 4; reg++) {
        const int t = t0 + rh * 64 + 16 * r + 4 * quad + reg;
        ob[(size_t)t * E_EXP + e] = acc[r][c][reg];
      }
    }
}

// ---------------- wave helpers ----------------
__device__ inline uint32_t ordkey(float v) {
  uint32_t b = __float_as_uint(v);
  return (b & 0x80000000u) ? ~b : (b | 0x80000000u);
}
__device__ inline float inv_ordkey(uint32_t k) {
  return (k & 0x80000000u) ? __uint_as_float(k & 0x7fffffffu) : __uint_as_float(~k);
}
__device__ inline uint32_t wave_max_u32(uint32_t v) {
  #pragma unroll
  for (int off = 32; off > 0; off >>= 1) {
    uint32_t o = __shfl_xor(v, off, 64);
    v = (o > v) ? o : v;
  }
  return v;
}
__device__ inline unsigned long long wave_max_u64(unsigned long long v) {
  #pragma unroll
  for (int off = 32; off > 0; off >>= 1) {
    unsigned long long o = __shfl_xor(v, off, 64);
    v = (o > v) ? o : v;
  }
  return v;
}
__device__ inline float wave_max_f32(float v) {
  #pragma unroll
  for (int off = 32; off > 0; off >>= 1) v = fmaxf(v, __shfl_xor(v, off, 64));
  return v;
}
__device__ inline float wave_sum_f32(float v) {
  #pragma unroll
  for (int off = 32; off > 0; off >>= 1) v += __shfl_xor(v, off, 64);
  return v;
}
__device__ inline double wave_sum_f64(double v) {
  #pragma unroll
  for (int off = 32; off > 0; off >>= 1) v += __shfl_xor(v, off, 64);
  return v;
}

// ---------------- route: sum 2 partials, 32-bit-key top-8 via ballot ----------------
// Selection semantics identical to the 64-bit packed-key scheme: highest key wins;
// ties -> slot0 (experts 0..63) preferred, lowest lane within slot (= lowest expert
// index, matching jax.lax.top_k). Exact bit-ties give gap=0 < TAU -> f64 recompute.
__global__ __launch_bounds__(256) void route_kernel(float* out,
                                                    int* flag_cnt, int* flags,
                                                    uint32_t fk0, uint32_t fk1) {
  const int lane = threadIdx.x & 63;
  const int t = blockIdx.x * 4 + (threadIdx.x >> 6);
  const size_t base = (size_t)t * E_EXP;
  float* mask_o   = out;
  float* probs_o  = out + TE;
  float* lclean_o = out + 2 * TE;
  float* lsel_o   = out + 3 * TE;

  double a0 = 0.0, a1 = 0.0;
  #pragma unroll
  for (int s = 0; s < NSPLIT; s++) {
    a0 += (double)out[(size_t)s * TE + base + lane];
    a1 += (double)out[(size_t)s * TE + base + lane + 64];
  }
  const float lc0 = (float)a0, lc1 = (float)a1;

  const float ls0 = lc0 + gumbel_f32((uint32_t)(base + lane), fk0, fk1);
  const float ls1 = lc1 + gumbel_f32((uint32_t)(base + lane + 64), fk0, fk1);

  const uint32_t key0 = ordkey(ls0);
  const uint32_t key1 = ordkey(ls1);
  bool sel0 = false, sel1 = false;
  uint32_t w8 = 0;
  #pragma unroll
  for (int it = 0; it < 8; ++it) {
    uint32_t k0v = sel0 ? 0u : key0;
    uint32_t k1v = sel1 ? 0u : key1;
    w8 = wave_max_u32(k0v > k1v ? k0v : k1v);
    unsigned long long b0 = __ballot(k0v == w8);
    if (b0) {
      if (lane == __ffsll(b0) - 1) sel0 = true;
    } else {
      unsigned long long b1 = __ballot(k1v == w8);
      if (lane == __ffsll(b1) - 1) sel1 = true;
    }
  }
  {
    uint32_t k0v = sel0 ? 0u : key0;
    uint32_t k1v = sel1 ? 0u : key1;
    uint32_t w9 = wave_max_u32(k0v > k1v ? k0v : k1v);
    float gap = inv_ordkey(w8) - inv_ordkey(w9);
    if (lane == 0 && gap < TAU) {
      int idx = atomicAdd(flag_cnt, 1);
      if (idx < FLAG_CAP) flags[idx] = t;
    }
  }

  float mx = wave_max_f32(fmaxf(lc0, lc1));
  float p0 = __expf(lc0 - mx);
  float p1 = __expf(lc1 - mx);
  float s8 = wave_sum_f32((sel0 ? p0 : 0.f) + (sel1 ? p1 : 0.f));

  lclean_o[base + lane]       = lc0;
  lclean_o[base + lane + 64]  = lc1;
  lsel_o[base + lane]         = ls0;
  lsel_o[base + lane + 64]    = ls1;
  mask_o[base + lane]         = sel0 ? 1.0f : 0.0f;
  mask_o[base + lane + 64]    = sel1 ? 1.0f : 0.0f;
  probs_o[base + lane]        = sel0 ? (p0 / s8) : 0.0f;
  probs_o[base + lane + 64]   = sel1 ? (p1 / s8) : 0.0f;
}

// ---------------- fp64 recompute of flagged tokens (8-way ILP) ----------------
__global__ __launch_bounds__(256) void recompute_kernel(const float* __restrict__ h,
                                                        const float* __restrict__ W,
                                                        const int* __restrict__ flag_cnt,
                                                        const int* __restrict__ flags,
                                                        float* __restrict__ mask_out,
                                                        float* __restrict__ probs_out,
                                                        float* __restrict__ lclean_out,
                                                        float* __restrict__ lsel_out,
                                                        uint32_t fk0, uint32_t fk1) {
  __shared__ __align__(16) float shf[D_DIM];
  __shared__ double dsum[E_EXP];
  __shared__ float larr[E_EXP];
  const int tid = threadIdx.x;
  int cnt = *flag_cnt;
  if (cnt > FLAG_CAP) cnt = FLAG_CAP;

  for (int ii = blockIdx.x; ii < cnt; ii += gridDim.x) {
    const int t = flags[ii];
    #pragma unroll
    for (int s = 0; s < 4; s++) {
      int f4 = s * 256 + tid;
      *(float4*)&shf[f4 * 4] = *(const float4*)(h + (size_t)t * D_DIM + f4 * 4);
    }
    __syncthreads();

    const int e = tid & 127;
    const int half = tid >> 7;
    const int kb = half * (D_DIM / 2);
    double acc[8];
    #pragma unroll
    for (int j = 0; j < 8; j++) acc[j] = 0.0;
    #pragma unroll 2
    for (int k = 0; k < D_DIM / 2; k += 8) {
      #pragma unroll
      for (int j = 0; j < 8; j++) {
        int kk = kb + k + j;
        acc[j] = fma((double)shf[kk], (double)W[(size_t)kk * E_EXP + e], acc[j]);
      }
    }
    double a = ((acc[0] + acc[1]) + (acc[2] + acc[3])) + ((acc[4] + acc[5]) + (acc[6] + acc[7]));
    if (half == 1) dsum[e] = a;
    __syncthreads();
    if (half == 0) {
      float lc = (float)(a + dsum[e]);
      larr[e] = lc;
      lclean_out[(size_t)t * E_EXP + e] = lc;
    }
    __syncthreads();

    if (tid < 64) {
      const size_t base = (size_t)t * E_EXP;
      const int lane = tid;
      float lc0 = larr[lane], lc1 = larr[lane + 64];
      float ls0 = lc0 + (float)gumbel_f64((uint32_t)(base + lane), fk0, fk1);
      float ls1 = lc1 + (float)gumbel_f64((uint32_t)(base + lane + 64), fk0, fk1);
      lsel_out[base + lane]      = ls0;
      lsel_out[base + lane + 64] = ls1;

      unsigned long long pk0 = (((unsigned long long)ordkey(ls0)) << 32) | (unsigned)(127 - lane);
      unsigned long long pk1 = (((unsigned long long)ordkey(ls1)) << 32) | (unsigned)(63 - lane);
      bool sel0 = false, sel1 = false;
      #pragma unroll
      for (int it = 0; it < 8; ++it) {
        unsigned long long cc0 = sel0 ? 0ull : pk0;
        unsigned long long cc1 = sel1 ? 0ull : pk1;
        unsigned long long mm = wave_max_u64(cc0 > cc1 ? cc0 : cc1);
        int ew = 127 - (int)(mm & 0xffull);
        if (ew == lane)      sel0 = true;
        if (ew == lane + 64) sel1 = true;
      }
      float mx = wave_max_f32(fmaxf(lc0, lc1));
      double pd0 = exp((double)lc0 - (double)mx);
      double pd1 = exp((double)lc1 - (double)mx);
      double s8 = wave_sum_f64((sel0 ? pd0 : 0.0) + (sel1 ? pd1 : 0.0));

      mask_out[base + lane]       = sel0 ? 1.0f : 0.0f;
      mask_out[base + lane + 64]  = sel1 ? 1.0f : 0.0f;
      probs_out[base + lane]      = sel0 ? (float)(pd0 / s8) : 0.0f;
      probs_out[base + lane + 64] = sel1 ? (float)(pd1 / s8) : 0.0f;
    }
    __syncthreads();
  }
}

extern "C" void kernel_launch(void* const* d_in, const int* in_sizes, int n_in,
                              void* d_out, int out_size, void* d_ws, size_t ws_size,
                              hipStream_t stream) {
  const float* h = (const float*)d_in[0];
  const float* W = (const float*)d_in[1];

  float* out      = (float*)d_out;
  float* mask_o   = out;
  float* probs_o  = out + TE;
  float* lclean_o = out + 2 * TE;
  float* lsel_o   = out + 3 * TE;

  int* wsi   = (int*)d_ws;
  int* flags = wsi + 16;
  _Float16* WF16 = (_Float16*)((char*)d_ws + WT_OFF);

  uint32_t fk0, fk1;
  tf2x32(0u, 7u, 0u, 1u, &fk0, &fk1);

  prep_kernel<<<256, 256, 0, stream>>>(W, WF16, wsi);
  gemm_mfma<<<dim3(T_TOK / BMg, NSPLIT), 512, 0, stream>>>(h, WF16, out);
  route_kernel<<<T_TOK / 4, 256, 0, stream>>>(out, wsi, flags, fk0, fk1);
  recompute_kernel<<<256, 256, 0, stream>>>(h, W, wsi, flags, mask_o, probs_o, lclean_o, lsel_o,
                                            fk0, fk1);
}

// Round 6
// 487.167 us; speedup vs baseline: 1.0626x; 1.0626x over previous
//
#include <hip/hip_runtime.h>
#include <stdint.h>

#define T_TOK 16384
#define D_DIM 4096
#define E_EXP 128
#define TE ((size_t)T_TOK * E_EXP)

#define TAU 3e-4f
#define FLAG_CAP 8192
#define WT_OFF 65536
#define WT_ELEMS ((size_t)E_EXP * D_DIM)   // 524288 per array

#define NSPLIT 2
#define KLEN (D_DIM / NSPLIT)              // 2048
#define BMg 128
#define BKg 64

typedef __attribute__((ext_vector_type(8))) short short8;
typedef __attribute__((ext_vector_type(4))) float f32x4;

// ---------------- Threefry-2x32 (JAX-compatible) ----------------
#define TF_ROUND(x0, x1, r) { x0 += x1; x1 = (x1 << r) | (x1 >> (32 - r)); x1 ^= x0; }

__host__ __device__ inline void tf2x32(uint32_t k0, uint32_t k1, uint32_t x0, uint32_t x1,
                                       uint32_t* o0, uint32_t* o1) {
  uint32_t ks2 = k0 ^ k1 ^ 0x1BD11BDAu;
  x0 += k0; x1 += k1;
  TF_ROUND(x0, x1, 13) TF_ROUND(x0, x1, 15) TF_ROUND(x0, x1, 26) TF_ROUND(x0, x1, 6)
  x0 += k1; x1 += ks2 + 1u;
  TF_ROUND(x0, x1, 17) TF_ROUND(x0, x1, 29) TF_ROUND(x0, x1, 16) TF_ROUND(x0, x1, 24)
  x0 += ks2; x1 += k0 + 2u;
  TF_ROUND(x0, x1, 13) TF_ROUND(x0, x1, 15) TF_ROUND(x0, x1, 26) TF_ROUND(x0, x1, 6)
  x0 += k0; x1 += k1 + 3u;
  TF_ROUND(x0, x1, 17) TF_ROUND(x0, x1, 29) TF_ROUND(x0, x1, 16) TF_ROUND(x0, x1, 24)
  x0 += k1; x1 += ks2 + 4u;
  TF_ROUND(x0, x1, 13) TF_ROUND(x0, x1, 15) TF_ROUND(x0, x1, 26) TF_ROUND(x0, x1, 6)
  x0 += ks2; x1 += k0 + 5u;
  *o0 = x0; *o1 = x1;
}

__device__ inline uint32_t rng_bits(uint32_t j, uint32_t fk0, uint32_t fk1) {
  uint32_t o0, o1;
  tf2x32(fk0, fk1, 0u, j, &o0, &o1);
  return o0 ^ o1;
}

// gumbel = -log(-log(u)). Inner log kept precise (near u~1 its absolute error is
// amplified by the outer log); outer log's near-1 region maps to gumbel~0 where
// absolute error stays ~1e-7, so the fast hw log is safe there.
__device__ inline float gumbel_f32(uint32_t j, uint32_t fk0, uint32_t fk1) {
  uint32_t bits = rng_bits(j, fk0, fk1);
  float f = __uint_as_float((bits >> 9) | 0x3f800000u) - 1.0f;
  const float mn = 1e-6f;
  const float mx = (float)(1.0 - 1e-6);
  float u = fmaxf(mn, f * (mx - mn) + mn);
  float nl = -logf(u);
  return -__logf(nl);
}

__device__ inline double gumbel_f64(uint32_t j, uint32_t fk0, uint32_t fk1) {
  uint32_t bits = rng_bits(j, fk0, fk1);
  float f = __uint_as_float((bits >> 9) | 0x3f800000u) - 1.0f;
  const float mn = 1e-6f;
  const float mx = (float)(1.0 - 1e-6);
  float u = fmaxf(mn, f * (mx - mn) + mn);
  return -log(-log((double)u));
}

// ---------------- bf16 split helpers ----------------
__device__ inline unsigned short f2bf(float x) {        // round-nearest-even
  uint32_t u = __float_as_uint(x);
  return (unsigned short)((u + 0x7fffu + ((u >> 16) & 1u)) >> 16);
}
__device__ inline float bf2f(unsigned short h) { return __uint_as_float(((uint32_t)h) << 16); }

// async global->LDS, 16B per lane; LDS dest must be wave-uniform base (+lane*16 implicit)
__device__ __forceinline__ void gload_lds16(const unsigned short* g, unsigned short* l) {
  __builtin_amdgcn_global_load_lds(
      (const __attribute__((address_space(1))) unsigned int*)g,
      (__attribute__((address_space(3))) unsigned int*)l, 16, 0, 0);
}

// ---------------- prep: W[k][e] -> fragment-order bf16 hi/lo ----------------
// Slot (kb 0..127, cg 0..7, ln 0..63) holds W[kb*32 + (ln>>4)*8 + j][cg*16 + (ln&15)],
// j=0..7, at linear offset slot*8. This is exactly the MFMA B-fragment order, so the
// GEMM's LDS staging is a pure linear 16B/lane copy (conflict-free both ends).
__global__ __launch_bounds__(256) void prep_kernel(const float* __restrict__ W,
                                                   unsigned short* __restrict__ WFhi,
                                                   unsigned short* __restrict__ WFlo,
                                                   int* __restrict__ wsi) {
  if (blockIdx.x == 0 && threadIdx.x < 16) wsi[threadIdx.x] = 0;
  const int gslot = blockIdx.x * 256 + threadIdx.x;   // 0..65535
  const int kb  = gslot >> 9;
  const int rem = gslot & 511;
  const int cg  = rem >> 6;
  const int ln  = rem & 63;
  const int q = ln >> 4, m = ln & 15;
  const int e  = cg * 16 + m;
  const int k0 = kb * 32 + q * 8;

  __attribute__((aligned(16))) unsigned short hi[8];
  __attribute__((aligned(16))) unsigned short lo[8];
  #pragma unroll
  for (int j = 0; j < 8; j++) {
    float w = W[(size_t)(k0 + j) * E_EXP + e];
    unsigned short h16 = f2bf(w);
    hi[j] = h16;
    lo[j] = f2bf(w - bf2f(h16));
  }
  *(uint4*)(WFhi + (size_t)gslot * 8) = *(const uint4*)hi;
  *(uint4*)(WFlo + (size_t)gslot * 8) = *(const uint4*)lo;
}

// ---------------- MFMA GEMM: 128x128 tile, 8 waves (2x4), BK=64, split-K=2 ----------------
// 2-phase double-buffered pipeline, 512 threads, 32 K-steps:
//   issue next B via global_load_lds (2 per array) + next A (64B) into regs
//   -> compute current (24 ds_read_b128 + 48 MFMA per wave)
//   -> convert/ds_write next A -> one barrier per K-step.
// BK=64 halves the barrier count vs BK=32 and doubles the MFMA phase length
// (~1000+ cyc) past the ~900-cyc HBM miss latency of the A loads, so the
// prefetch fully hides. LDS = 128 KB (4 arrays x 2 buf x 16 KB), 1 block/CU, 8 waves.
// (R4-verified at 497.4 us; fp16x2 variant regressed -- MFMA count is not the
// critical path here, the covering schedule is.)
__global__ __launch_bounds__(512, 2) void gemm_mfma(const float* __restrict__ h,
                                                    const unsigned short* __restrict__ WFhi,
                                                    const unsigned short* __restrict__ WFlo,
                                                    float* __restrict__ outbase) {
  __shared__ __align__(16) unsigned short sAhi[2][8192];   // 16 KB per buf, fragment order
  __shared__ __align__(16) unsigned short sAlo[2][8192];
  __shared__ __align__(16) unsigned short sBhi[2][8192];
  __shared__ __align__(16) unsigned short sBlo[2][8192];

  const int tid  = threadIdx.x;        // 0..511
  const int ln   = tid & 63;
  const int wv   = tid >> 6;           // 0..7
  const int m    = ln & 15;
  const int quad = ln >> 4;
  const int rh   = wv >> 2;            // token half (0/1)
  const int ch   = wv & 3;             // expert quarter (0..3)
  const int t0   = blockIdx.x * BMg;
  const int kbase = blockIdx.y * KLEN;

  // A staging: thread fills fragment slots tid (k-slice 0) and tid+512 (k-slice 1),
  // both for row wv*16+m, k columns quad*8+{0..7} and 32+quad*8+{0..7}.
  const float* asrc = h + (size_t)(t0 + wv * 16 + m) * D_DIM + kbase + quad * 8;

  // B staging: two 8KB gload passes per array cover 8192 shorts (2 k-blocks, contiguous
  // in the fragment-order global layout).
  const size_t gslot8 = (size_t)tid * 8;                   // shorts
  unsigned short* bdst_h[2][2] = {{ &sBhi[0][wv * 512], &sBhi[0][4096 + wv * 512] },
                                  { &sBhi[1][wv * 512], &sBhi[1][4096 + wv * 512] }};
  unsigned short* bdst_l[2][2] = {{ &sBlo[0][wv * 512], &sBlo[0][4096 + wv * 512] },
                                  { &sBlo[1][wv * 512], &sBlo[1][4096 + wv * 512] }};

  f32x4 acc[4][2];
  #pragma unroll
  for (int r = 0; r < 4; r++)
    #pragma unroll
    for (int c = 0; c < 2; c++) acc[r][c] = (f32x4){0.f, 0.f, 0.f, 0.f};

  // ---- prologue: stage k0 = 0 into buffer 0 ----
  {
    const size_t boff = ((size_t)(kbase >> 5)) * 4096;
    gload_lds16(WFhi + boff + gslot8,        bdst_h[0][0]);
    gload_lds16(WFhi + boff + 4096 + gslot8, bdst_h[0][1]);
    gload_lds16(WFlo + boff + gslot8,        bdst_l[0][0]);
    gload_lds16(WFlo + boff + 4096 + gslot8, bdst_l[0][1]);

    float4 a0 = *(const float4*)(asrc);
    float4 a1 = *(const float4*)(asrc + 4);
    float4 a2 = *(const float4*)(asrc + 32);
    float4 a3 = *(const float4*)(asrc + 36);
    float v0[8] = {a0.x, a0.y, a0.z, a0.w, a1.x, a1.y, a1.z, a1.w};
    float v1[8] = {a2.x, a2.y, a2.z, a2.w, a3.x, a3.y, a3.z, a3.w};
    __attribute__((aligned(16))) unsigned short h0[8], l0[8], h1[8], l1[8];
    #pragma unroll
    for (int j = 0; j < 8; j++) {
      unsigned short t16 = f2bf(v0[j]); h0[j] = t16; l0[j] = f2bf(v0[j] - bf2f(t16));
      t16 = f2bf(v1[j]);                h1[j] = t16; l1[j] = f2bf(v1[j] - bf2f(t16));
    }
    *(uint4*)&sAhi[0][(size_t)tid * 8]         = *(const uint4*)h0;
    *(uint4*)&sAlo[0][(size_t)tid * 8]         = *(const uint4*)l0;
    *(uint4*)&sAhi[0][(size_t)(tid + 512) * 8] = *(const uint4*)h1;
    *(uint4*)&sAlo[0][(size_t)(tid + 512) * 8] = *(const uint4*)l1;
    __syncthreads();   // drains vmcnt(0) (B DMA) + lgkm (A writes)
  }

  int cur = 0;
  for (int k0 = 0; k0 < KLEN; k0 += BKg) {
    const int kn  = k0 + BKg;
    const bool nxt = (kn < KLEN);
    float4 a0, a1, a2, a3;

    if (nxt) {
      // issue next-tile B straight to LDS (other buffer) + next A into regs
      const int nb = cur ^ 1;
      const size_t boff = ((size_t)((kbase + kn) >> 5)) * 4096;
      gload_lds16(WFhi + boff + gslot8,        bdst_h[nb][0]);
      gload_lds16(WFhi + boff + 4096 + gslot8, bdst_h[nb][1]);
      gload_lds16(WFlo + boff + gslot8,        bdst_l[nb][0]);
      gload_lds16(WFlo + boff + 4096 + gslot8, bdst_l[nb][1]);
      a0 = *(const float4*)(asrc + kn);
      a1 = *(const float4*)(asrc + kn + 4);
      a2 = *(const float4*)(asrc + kn + 32);
      a3 = *(const float4*)(asrc + kn + 36);
    }

    // ---- compute current buffer: 2 k-slices x (r4 x c2) x 3 MFMA ----
    short8 ahi[4][2], alo[4][2], bhi[2][2], blo[2][2];
    #pragma unroll
    for (int ks = 0; ks < 2; ks++) {
      #pragma unroll
      for (int r = 0; r < 4; r++) {
        const int slot = (ks * 512 + (rh * 4 + r) * 64 + ln) * 8;
        ahi[r][ks] = *(const short8*)&sAhi[cur][slot];
        alo[r][ks] = *(const short8*)&sAlo[cur][slot];
      }
      #pragma unroll
      for (int c = 0; c < 2; c++) {
        const int slot = (ks * 512 + (ch * 2 + c) * 64 + ln) * 8;
        bhi[c][ks] = *(const short8*)&sBhi[cur][slot];
        blo[c][ks] = *(const short8*)&sBlo[cur][slot];
      }
    }
    #pragma unroll
    for (int ks = 0; ks < 2; ks++)
      #pragma unroll
      for (int r = 0; r < 4; r++)
        #pragma unroll
        for (int c = 0; c < 2; c++) {
          acc[r][c] = __builtin_amdgcn_mfma_f32_16x16x32_bf16(ahi[r][ks], bhi[c][ks], acc[r][c], 0, 0, 0);
          acc[r][c] = __builtin_amdgcn_mfma_f32_16x16x32_bf16(ahi[r][ks], blo[c][ks], acc[r][c], 0, 0, 0);
          acc[r][c] = __builtin_amdgcn_mfma_f32_16x16x32_bf16(alo[r][ks], bhi[c][ks], acc[r][c], 0, 0, 0);
        }

    if (nxt) {
      // convert + write next A late (loads had the whole MFMA phase to land)
      const int nb = cur ^ 1;
      float v0[8] = {a0.x, a0.y, a0.z, a0.w, a1.x, a1.y, a1.z, a1.w};
      float v1[8] = {a2.x, a2.y, a2.z, a2.w, a3.x, a3.y, a3.z, a3.w};
      __attribute__((aligned(16))) unsigned short h0[8], l0[8], h1[8], l1[8];
      #pragma unroll
      for (int j = 0; j < 8; j++) {
        unsigned short t16 = f2bf(v0[j]); h0[j] = t16; l0[j] = f2bf(v0[j] - bf2f(t16));
        t16 = f2bf(v1[j]);                h1[j] = t16; l1[j] = f2bf(v1[j] - bf2f(t16));
      }
      *(uint4*)&sAhi[nb][(size_t)tid * 8]         = *(const uint4*)h0;
      *(uint4*)&sAlo[nb][(size_t)tid * 8]         = *(const uint4*)l0;
      *(uint4*)&sAhi[nb][(size_t)(tid + 512) * 8] = *(const uint4*)h1;
      *(uint4*)&sAlo[nb][(size_t)(tid + 512) * 8] = *(const uint4*)l1;
    }
    __syncthreads();   // one barrier per K-step: drains B DMA + A writes
    cur ^= 1;
  }

  // partials for split s go straight into output region s (route re-reads + overwrites)
  float* ob = outbase + (size_t)blockIdx.y * TE;
  #pragma unroll
  for (int r = 0; r < 4; r++)
    #pragma unroll
    for (int c = 0; c < 2; c++) {
      const int e = ch * 32 + 16 * c + m;
      #pragma unroll
      for (int reg = 0; reg < 4; reg++) {
        const int t = t0 + rh * 64 + 16 * r + 4 * quad + reg;
        ob[(size_t)t * E_EXP + e] = acc[r][c][reg];
      }
    }
}

// ---------------- wave helpers ----------------
__device__ inline uint32_t ordkey(float v) {
  uint32_t b = __float_as_uint(v);
  return (b & 0x80000000u) ? ~b : (b | 0x80000000u);
}
__device__ inline float inv_ordkey(uint32_t k) {
  return (k & 0x80000000u) ? __uint_as_float(k & 0x7fffffffu) : __uint_as_float(~k);
}
__device__ inline uint32_t wave_max_u32(uint32_t v) {
  #pragma unroll
  for (int off = 32; off > 0; off >>= 1) {
    uint32_t o = __shfl_xor(v, off, 64);
    v = (o > v) ? o : v;
  }
  return v;
}
__device__ inline unsigned long long wave_max_u64(unsigned long long v) {
  #pragma unroll
  for (int off = 32; off > 0; off >>= 1) {
    unsigned long long o = __shfl_xor(v, off, 64);
    v = (o > v) ? o : v;
  }
  return v;
}
__device__ inline float wave_max_f32(float v) {
  #pragma unroll
  for (int off = 32; off > 0; off >>= 1) v = fmaxf(v, __shfl_xor(v, off, 64));
  return v;
}
__device__ inline float wave_sum_f32(float v) {
  #pragma unroll
  for (int off = 32; off > 0; off >>= 1) v += __shfl_xor(v, off, 64);
  return v;
}
__device__ inline double wave_sum_f64(double v) {
  #pragma unroll
  for (int off = 32; off > 0; off >>= 1) v += __shfl_xor(v, off, 64);
  return v;
}

// ---------------- route: sum 2 partials, 32-bit-key top-8 via ballot ----------------
// Selection semantics identical to the 64-bit packed-key scheme: highest key wins;
// ties -> slot0 (experts 0..63) preferred, lowest lane within slot (= lowest expert
// index, matching jax.lax.top_k). Exact bit-ties give gap=0 < TAU -> f64 recompute.
__global__ __launch_bounds__(256) void route_kernel(float* out,
                                                    int* flag_cnt, int* flags,
                                                    uint32_t fk0, uint32_t fk1) {
  const int lane = threadIdx.x & 63;
  const int t = blockIdx.x * 4 + (threadIdx.x >> 6);
  const size_t base = (size_t)t * E_EXP;
  float* mask_o   = out;
  float* probs_o  = out + TE;
  float* lclean_o = out + 2 * TE;
  float* lsel_o   = out + 3 * TE;

  double a0 = 0.0, a1 = 0.0;
  #pragma unroll
  for (int s = 0; s < NSPLIT; s++) {
    a0 += (double)out[(size_t)s * TE + base + lane];
    a1 += (double)out[(size_t)s * TE + base + lane + 64];
  }
  const float lc0 = (float)a0, lc1 = (float)a1;

  const float ls0 = lc0 + gumbel_f32((uint32_t)(base + lane), fk0, fk1);
  const float ls1 = lc1 + gumbel_f32((uint32_t)(base + lane + 64), fk0, fk1);

  const uint32_t key0 = ordkey(ls0);
  const uint32_t key1 = ordkey(ls1);
  bool sel0 = false, sel1 = false;
  uint32_t w8 = 0;
  #pragma unroll
  for (int it = 0; it < 8; ++it) {
    uint32_t k0v = sel0 ? 0u : key0;
    uint32_t k1v = sel1 ? 0u : key1;
    w8 = wave_max_u32(k0v > k1v ? k0v : k1v);
    unsigned long long b0 = __ballot(k0v == w8);
    if (b0) {
      if (lane == __ffsll(b0) - 1) sel0 = true;
    } else {
      unsigned long long b1 = __ballot(k1v == w8);
      if (lane == __ffsll(b1) - 1) sel1 = true;
    }
  }
  {
    uint32_t k0v = sel0 ? 0u : key0;
    uint32_t k1v = sel1 ? 0u : key1;
    uint32_t w9 = wave_max_u32(k0v > k1v ? k0v : k1v);
    float gap = inv_ordkey(w8) - inv_ordkey(w9);
    if (lane == 0 && gap < TAU) {
      int idx = atomicAdd(flag_cnt, 1);
      if (idx < FLAG_CAP) flags[idx] = t;
    }
  }

  float mx = wave_max_f32(fmaxf(lc0, lc1));
  float p0 = __expf(lc0 - mx);
  float p1 = __expf(lc1 - mx);
  float s8 = wave_sum_f32((sel0 ? p0 : 0.f) + (sel1 ? p1 : 0.f));

  lclean_o[base + lane]       = lc0;
  lclean_o[base + lane + 64]  = lc1;
  lsel_o[base + lane]         = ls0;
  lsel_o[base + lane + 64]    = ls1;
  mask_o[base + lane]         = sel0 ? 1.0f : 0.0f;
  mask_o[base + lane + 64]    = sel1 ? 1.0f : 0.0f;
  probs_o[base + lane]        = sel0 ? (p0 / s8) : 0.0f;
  probs_o[base + lane + 64]   = sel1 ? (p1 / s8) : 0.0f;
}

// ---------------- fp64 recompute of flagged tokens (8-way ILP) ----------------
__global__ __launch_bounds__(256) void recompute_kernel(const float* __restrict__ h,
                                                        const float* __restrict__ W,
                                                        const int* __restrict__ flag_cnt,
                                                        const int* __restrict__ flags,
                                                        float* __restrict__ mask_out,
                                                        float* __restrict__ probs_out,
                                                        float* __restrict__ lclean_out,
                                                        float* __restrict__ lsel_out,
                                                        uint32_t fk0, uint32_t fk1) {
  __shared__ __align__(16) float shf[D_DIM];
  __shared__ double dsum[E_EXP];
  __shared__ float larr[E_EXP];
  const int tid = threadIdx.x;
  int cnt = *flag_cnt;
  if (cnt > FLAG_CAP) cnt = FLAG_CAP;

  for (int ii = blockIdx.x; ii < cnt; ii += gridDim.x) {
    const int t = flags[ii];
    #pragma unroll
    for (int s = 0; s < 4; s++) {
      int f4 = s * 256 + tid;
      *(float4*)&shf[f4 * 4] = *(const float4*)(h + (size_t)t * D_DIM + f4 * 4);
    }
    __syncthreads();

    const int e = tid & 127;
    const int half = tid >> 7;
    const int kb = half * (D_DIM / 2);
    double acc[8];
    #pragma unroll
    for (int j = 0; j < 8; j++) acc[j] = 0.0;
    #pragma unroll 2
    for (int k = 0; k < D_DIM / 2; k += 8) {
      #pragma unroll
      for (int j = 0; j < 8; j++) {
        int kk = kb + k + j;
        acc[j] = fma((double)shf[kk], (double)W[(size_t)kk * E_EXP + e], acc[j]);
      }
    }
    double a = ((acc[0] + acc[1]) + (acc[2] + acc[3])) + ((acc[4] + acc[5]) + (acc[6] + acc[7]));
    if (half == 1) dsum[e] = a;
    __syncthreads();
    if (half == 0) {
      float lc = (float)(a + dsum[e]);
      larr[e] = lc;
      lclean_out[(size_t)t * E_EXP + e] = lc;
    }
    __syncthreads();

    if (tid < 64) {
      const size_t base = (size_t)t * E_EXP;
      const int lane = tid;
      float lc0 = larr[lane], lc1 = larr[lane + 64];
      float ls0 = lc0 + (float)gumbel_f64((uint32_t)(base + lane), fk0, fk1);
      float ls1 = lc1 + (float)gumbel_f64((uint32_t)(base + lane + 64), fk0, fk1);
      lsel_out[base + lane]      = ls0;
      lsel_out[base + lane + 64] = ls1;

      unsigned long long pk0 = (((unsigned long long)ordkey(ls0)) << 32) | (unsigned)(127 - lane);
      unsigned long long pk1 = (((unsigned long long)ordkey(ls1)) << 32) | (unsigned)(63 - lane);
      bool sel0 = false, sel1 = false;
      #pragma unroll
      for (int it = 0; it < 8; ++it) {
        unsigned long long cc0 = sel0 ? 0ull : pk0;
        unsigned long long cc1 = sel1 ? 0ull : pk1;
        unsigned long long mm = wave_max_u64(cc0 > cc1 ? cc0 : cc1);
        int ew = 127 - (int)(mm & 0xffull);
        if (ew == lane)      sel0 = true;
        if (ew == lane + 64) sel1 = true;
      }
      float mx = wave_max_f32(fmaxf(lc0, lc1));
      double pd0 = exp((double)lc0 - (double)mx);
      double pd1 = exp((double)lc1 - (double)mx);
      double s8 = wave_sum_f64((sel0 ? pd0 : 0.0) + (sel1 ? pd1 : 0.0));

      mask_out[base + lane]       = sel0 ? 1.0f : 0.0f;
      mask_out[base + lane + 64]  = sel1 ? 1.0f : 0.0f;
      probs_out[base + lane]      = sel0 ? (float)(pd0 / s8) : 0.0f;
      probs_out[base + lane + 64] = sel1 ? (float)(pd1 / s8) : 0.0f;
    }
    __syncthreads();
  }
}

extern "C" void kernel_launch(void* const* d_in, const int* in_sizes, int n_in,
                              void* d_out, int out_size, void* d_ws, size_t ws_size,
                              hipStream_t stream) {
  const float* h = (const float*)d_in[0];
  const float* W = (const float*)d_in[1];

  float* out      = (float*)d_out;
  float* mask_o   = out;
  float* probs_o  = out + TE;
  float* lclean_o = out + 2 * TE;
  float* lsel_o   = out + 3 * TE;

  int* wsi   = (int*)d_ws;
  int* flags = wsi + 16;
  unsigned short* WFhi = (unsigned short*)((char*)d_ws + WT_OFF);
  unsigned short* WFlo = WFhi + WT_ELEMS;

  uint32_t fk0, fk1;
  tf2x32(0u, 7u, 0u, 1u, &fk0, &fk1);

  prep_kernel<<<256, 256, 0, stream>>>(W, WFhi, WFlo, wsi);
  gemm_mfma<<<dim3(T_TOK / BMg, NSPLIT), 512, 0, stream>>>(h, WFhi, WFlo, out);
  route_kernel<<<T_TOK / 4, 256, 0, stream>>>(out, wsi, flags, fk0, fk1);
  recompute_kernel<<<256, 256, 0, stream>>>(h, W, wsi, flags, mask_o, probs_o, lclean_o, lsel_o,
                                            fk0, fk1);
}